// Round 4
// baseline (2472.625 us; speedup 1.0000x reference)
//
#include <hip/hip_runtime.h>
#include <hip/hip_bf16.h>
#include <stdint.h>

typedef unsigned short u16;
typedef __attribute__((ext_vector_type(8))) short bf16x8;
typedef __attribute__((ext_vector_type(4))) float f32x4;

#define BM 128
#define BN 128
#define BK 32

// ---------- helpers ----------
__device__ inline u16 f2bf(float f) {
  __hip_bfloat16 h = __float2bfloat16(f);
  return *reinterpret_cast<u16*>(&h);
}

typedef unsigned int __attribute__((address_space(1)))* gu32p;
typedef unsigned int __attribute__((address_space(3)))* lu32p;

__device__ inline void load_lds16(const void* g, void* l) {
  // async global->LDS, 16B per lane; LDS dest must be wave-uniform base (HW adds lane*16)
  __builtin_amdgcn_global_load_lds((gu32p)(uint64_t)g, (lu32p)(uint32_t)(uint64_t)l, 16, 0, 0);
}

template<int OP>  // 0 = sum, 1 = max
__device__ inline float block_reduce_256(float v, float* sbuf) {
  #pragma unroll
  for (int off = 32; off > 0; off >>= 1) {
    float o = __shfl_down(v, off);
    v = OP ? fmaxf(v, o) : (v + o);
  }
  const int lane = threadIdx.x & 63, w = threadIdx.x >> 6;
  if (lane == 0) sbuf[w] = v;
  __syncthreads();
  float r = OP ? fmaxf(fmaxf(sbuf[0], sbuf[1]), fmaxf(sbuf[2], sbuf[3]))
               : (sbuf[0] + sbuf[1] + sbuf[2] + sbuf[3]);
  __syncthreads();
  return r;
}

// ---------- GEMM: C[M,N] = A[M,K](bf16) * B[N,K](bf16)^T, batched via blockIdx.z ----------
// EPI: 0 = f32 out, 1 = bf16 out, 2 = +bias,relu -> bf16, 3 = +bias,+resid -> f32
template<int EPI>
__global__ __launch_bounds__(256, 2) void gemm_nt(
    const u16* __restrict__ A, const u16* __restrict__ B, void* Cv,
    const float* __restrict__ bias, const float* resid,
    int M, int N, int K, long long sA, long long sB, long long sC) {
  __shared__ u16 lds[BM * BK + BN * BK];  // 8KB + 8KB
  u16* As = lds;
  u16* Bs = lds + BM * BK;

  const int tid = threadIdx.x;
  const int lane = tid & 63, wave = tid >> 6;
  const int wr = wave >> 1, wc = wave & 1;
  const int lr = lane & 15, kq = lane >> 4;
  const int m0 = blockIdx.y * BM, n0 = blockIdx.x * BN;
  const int bz = blockIdx.z;
  const u16* Ab = A + (size_t)bz * sA;
  const u16* Bb = B + (size_t)bz * sB;

  f32x4 acc[4][4] = {};

  for (int kt = 0; kt < K; kt += BK) {
    // stage A tile (128x32 bf16 = 8KB = 2 issues of 256 lanes * 16B)
    #pragma unroll
    for (int i = 0; i < 2; ++i) {
      int t = i * 256 + tid;
      int row = t >> 2;                 // 64B per row (BK=32 bf16)
      int cb = (t & 3) * 16;            // byte within row
      const char* g = (const char*)(Ab + (size_t)(m0 + row) * K + kt) + cb;
      char* l = (char*)As + (size_t)(i * 256 + wave * 64) * 16;  // wave-uniform
      load_lds16(g, l);
    }
    #pragma unroll
    for (int i = 0; i < 2; ++i) {
      int t = i * 256 + tid;
      int row = t >> 2;
      int cb = (t & 3) * 16;
      const char* g = (const char*)(Bb + (size_t)(n0 + row) * K + kt) + cb;
      char* l = (char*)Bs + (size_t)(i * 256 + wave * 64) * 16;
      load_lds16(g, l);
    }
    __syncthreads();

    bf16x8 a[4], b[4];
    #pragma unroll
    for (int m = 0; m < 4; ++m)
      a[m] = *(const bf16x8*)(As + (wr * 64 + m * 16 + lr) * BK + kq * 8);
    #pragma unroll
    for (int n = 0; n < 4; ++n)
      b[n] = *(const bf16x8*)(Bs + (wc * 64 + n * 16 + lr) * BK + kq * 8);
    #pragma unroll
    for (int m = 0; m < 4; ++m)
      #pragma unroll
      for (int n = 0; n < 4; ++n)
        acc[m][n] = __builtin_amdgcn_mfma_f32_16x16x32_bf16(a[m], b[n], acc[m][n], 0, 0, 0);
    __syncthreads();
  }

  // epilogue: C/D layout col=lane&15, row=(lane>>4)*4+r  [verified m89]
  #pragma unroll
  for (int m = 0; m < 4; ++m) {
    int row = m0 + wr * 64 + m * 16 + kq * 4;
    #pragma unroll
    for (int n = 0; n < 4; ++n) {
      int col = n0 + wc * 64 + n * 16 + lr;
      #pragma unroll
      for (int r = 0; r < 4; ++r) {
        float v = acc[m][n][r];
        size_t idx = (size_t)sC * bz + (size_t)(row + r) * N + col;
        if (EPI == 0) {
          ((float*)Cv)[idx] = v;
        } else if (EPI == 1) {
          ((u16*)Cv)[idx] = f2bf(v);
        } else if (EPI == 2) {
          v += bias[col];
          ((u16*)Cv)[idx] = f2bf(v > 0.f ? v : 0.f);
        } else {
          ((float*)Cv)[idx] = resid[idx] + v + bias[col];
        }
      }
    }
  }
}

// ---------- LayerNorm (faithful buggy formula): out = (x - mu/sqrt(var)) * g + b, bf16 out ----------
__global__ __launch_bounds__(256) void ln_kernel(const float* __restrict__ x,
                                                 const float* __restrict__ g,
                                                 const float* __restrict__ b,
                                                 u16* __restrict__ out) {
  __shared__ float sbuf[4];
  size_t row = blockIdx.x;
  float4 v = ((const float4*)(x + row * 1024))[threadIdx.x];
  float s = v.x + v.y + v.z + v.w;
  float s2 = v.x * v.x + v.y * v.y + v.z * v.z + v.w * v.w;
  s = block_reduce_256<0>(s, sbuf);
  s2 = block_reduce_256<0>(s2, sbuf);
  float mu = s * (1.f / 1024.f);
  float var = (s2 - 1024.f * mu * mu) * (1.f / 1023.f);  // ddof=1
  float c = mu * rsqrtf(var);
  int col = threadIdx.x * 4;
  ushort4 o;
  o.x = f2bf((v.x - c) * g[col + 0] + b[col + 0]);
  o.y = f2bf((v.y - c) * g[col + 1] + b[col + 1]);
  o.z = f2bf((v.z - c) * g[col + 2] + b[col + 2]);
  o.w = f2bf((v.w - c) * g[col + 3] + b[col + 3]);
  ((ushort4*)(out + row * 1024))[threadIdx.x] = o;
}

// ---------- softmax over rows of S (1024 wide), scale applied pre-softmax, bf16 out ----------
__global__ __launch_bounds__(256) void softmax_kernel(const float* __restrict__ S,
                                                      u16* __restrict__ P) {
  __shared__ float sbuf[4];
  size_t row = blockIdx.x;
  const float scale = 0.03125f;  // 1/sqrt(1024)
  float4 v = ((const float4*)(S + row * 1024))[threadIdx.x];
  v.x *= scale; v.y *= scale; v.z *= scale; v.w *= scale;
  float mx = fmaxf(fmaxf(v.x, v.y), fmaxf(v.z, v.w));
  mx = block_reduce_256<1>(mx, sbuf);
  float e0 = __expf(v.x - mx), e1 = __expf(v.y - mx), e2 = __expf(v.z - mx), e3 = __expf(v.w - mx);
  float sum = block_reduce_256<0>(e0 + e1 + e2 + e3, sbuf);
  float inv = 1.f / sum;
  ushort4 o;
  o.x = f2bf(e0 * inv); o.y = f2bf(e1 * inv); o.z = f2bf(e2 * inv); o.w = f2bf(e3 * inv);
  ((ushort4*)(P + row * 1024))[threadIdx.x] = o;
}

// ---------- transposes ----------
__global__ void transpose_cvt_f32_bf16(const float* __restrict__ in, u16* __restrict__ out, int n) {
  __shared__ float t[32][33];
  int bx = blockIdx.x * 32, by = blockIdx.y * 32;
  int tx = threadIdx.x & 31, ty = threadIdx.x >> 5;
  for (int r = ty; r < 32; r += 8) t[r][tx] = in[(size_t)(by + r) * n + bx + tx];
  __syncthreads();
  for (int r = ty; r < 32; r += 8) out[(size_t)(bx + r) * n + by + tx] = f2bf(t[tx][r]);
}

__global__ void transpose_bf16_kernel(const u16* __restrict__ in, u16* __restrict__ out, int n) {
  __shared__ u16 t[32][33];
  size_t base = (size_t)blockIdx.z * n * n;
  int bx = blockIdx.x * 32, by = blockIdx.y * 32;
  int tx = threadIdx.x & 31, ty = threadIdx.x >> 5;
  for (int r = ty; r < 32; r += 8) t[r][tx] = in[base + (size_t)(by + r) * n + bx + tx];
  __syncthreads();
  for (int r = ty; r < 32; r += 8) out[base + (size_t)(bx + r) * n + by + tx] = t[tx][r];
}

// ---------- misc elementwise ----------
__global__ void cvt_f32_bf16(const float* __restrict__ in, u16* __restrict__ out, long long n4) {
  long long i = (long long)blockIdx.x * 256 + threadIdx.x;
  long long stride = (long long)gridDim.x * 256;
  for (; i < n4; i += stride) {
    float4 v = ((const float4*)in)[i];
    ushort4 o;
    o.x = f2bf(v.x); o.y = f2bf(v.y); o.z = f2bf(v.z); o.w = f2bf(v.w);
    ((ushort4*)out)[i] = o;
  }
}

__global__ void embed_kernel(const int* __restrict__ xTok, const float* __restrict__ enc,
                             float* __restrict__ z) {
  size_t row = blockIdx.x;
  int tok = xTok[row];
  float4 v = ((const float4*)(enc + (size_t)tok * 1024))[threadIdx.x];
  ((float4*)(z + row * 1024))[threadIdx.x] = v;
}

// ---------- loss ----------
__global__ __launch_bounds__(256) void nll_kernel(const float* __restrict__ logits,
                                                  const int* __restrict__ yTok,
                                                  float* __restrict__ nll) {
  __shared__ float sm[4];
  __shared__ float ss[4];
  size_t row = blockIdx.x;
  const float* L = logits + row * 32000;
  float m = -1e30f, s = 0.f;
  for (int i = threadIdx.x; i < 32000; i += 256) {
    float v = L[i];
    if (v > m) { s = s * __expf(m - v) + 1.f; m = v; }
    else       { s += __expf(v - m); }
  }
  #pragma unroll
  for (int off = 32; off > 0; off >>= 1) {
    float mo = __shfl_down(m, off), so = __shfl_down(s, off);
    float mn = fmaxf(m, mo);
    s = s * __expf(m - mn) + so * __expf(mo - mn);
    m = mn;
  }
  int lane = threadIdx.x & 63, w = threadIdx.x >> 6;
  if (lane == 0) { sm[w] = m; ss[w] = s; }
  __syncthreads();
  if (threadIdx.x == 0) {
    float M = fmaxf(fmaxf(sm[0], sm[1]), fmaxf(sm[2], sm[3]));
    float S = ss[0] * __expf(sm[0] - M) + ss[1] * __expf(sm[1] - M) +
              ss[2] * __expf(sm[2] - M) + ss[3] * __expf(sm[3] - M);
    float lse = M + logf(S);
    nll[row] = lse - L[yTok[row]];
  }
}

__global__ __launch_bounds__(256) void mean_kernel(const float* __restrict__ nll,
                                                   float* __restrict__ out) {
  __shared__ float sbuf[4];
  float s = 0.f;
  for (int i = threadIdx.x; i < 4096; i += 256) s += nll[i];
  s = block_reduce_256<0>(s, sbuf);
  if (threadIdx.x == 0) out[0] = s * (1.f / 4096.f);
}

// ---------- launch ----------
template<int EPI>
static void run_gemm(const void* A, const void* B, void* C, const float* bias, const float* resid,
                     int M, int N, int K, long long sA, long long sB, long long sC, int batches,
                     hipStream_t st) {
  dim3 g(N / BN, M / BM, batches);
  gemm_nt<EPI><<<g, dim3(256), 0, st>>>((const u16*)A, (const u16*)B, C, bias, resid,
                                        M, N, K, sA, sB, sC);
}

extern "C" void kernel_launch(void* const* d_in, const int* in_sizes, int n_in,
                              void* d_out, int out_size, void* d_ws, size_t ws_size,
                              hipStream_t stream) {
  const int*   xTok = (const int*)d_in[0];
  const int*   yTok = (const int*)d_in[1];
  const float* enc  = (const float*)d_in[2];
  const float* g1   = (const float*)d_in[3];
  const float* b1   = (const float*)d_in[4];
  const float* wq   = (const float*)d_in[5];
  const float* wk   = (const float*)d_in[6];
  const float* wv   = (const float*)d_in[7];
  const float* g2   = (const float*)d_in[8];
  const float* b2   = (const float*)d_in[9];
  const float* w1   = (const float*)d_in[10];
  const float* bb1  = (const float*)d_in[11];
  const float* w2   = (const float*)d_in[12];
  const float* bb2  = (const float*)d_in[13];

  const int Mr = 4096, D = 1024, V = 32000, L = 6;
  const long long MM = 1024 * 1024;

  size_t off = 0;
  auto alloc = [&](size_t bytes) -> void* {
    void* p = (char*)d_ws + off;
    off += (bytes + 255) & ~(size_t)255;
    return p;
  };
  // Live during the layer loop:
  float* z   = (float*)alloc((size_t)Mr * D * 4);    // 16MB  @ 0
  float* S   = (float*)alloc((size_t)Mr * 1024 * 4); // 16MB  @ 16M
  float* O   = (float*)alloc((size_t)Mr * D * 4);    // 16MB  @ 32M
  u16*   y1  = (u16*)alloc((size_t)Mr * D * 2);      //  8MB  @ 48M
  u16*   y2  = (u16*)alloc((size_t)Mr * D * 2);      //  8MB  @ 56M
  u16*   Qb  = (u16*)alloc((size_t)Mr * D * 2);      //  8MB  @ 64M
  u16*   Kb  = (u16*)alloc((size_t)Mr * D * 2);      //  8MB  @ 72M
  u16*   Vb  = (u16*)alloc((size_t)Mr * D * 2);      //  8MB  @ 80M
  u16*   Vt  = (u16*)alloc((size_t)Mr * D * 2);      //  8MB  @ 88M
  u16*   Pb  = (u16*)alloc((size_t)Mr * D * 2);      //  8MB  @ 96M
  u16*   wqT = (u16*)alloc((size_t)D * D * 2);
  u16*   wkT = (u16*)alloc((size_t)D * D * 2);
  u16*   wvT = (u16*)alloc((size_t)D * D * 2);
  u16*   w1T = (u16*)alloc((size_t)D * D * 2);
  u16*   w2T = (u16*)alloc((size_t)D * D * 2);
  float* nll = (float*)alloc(4096 * 4);
  u16*   Hb = Qb;   // reuse (Q dead after QK^T)
  // Post-loop aliases (everything S..Kb and Vb is dead once the last FF2 wrote z):
  u16*   encb = (u16*)S;   // 64MB span = S(16)+O(16)+y1(8)+y2(8)+Qb(8)+Kb(8)
  u16*   zb   = Vb;        // 8MB

  float* logits = (float*)d_out;
  float* lossp  = logits + (size_t)Mr * V;

  dim3 tb(256);
  transpose_cvt_f32_bf16<<<dim3(32, 32), tb, 0, stream>>>(wq, wqT, 1024);
  transpose_cvt_f32_bf16<<<dim3(32, 32), tb, 0, stream>>>(wk, wkT, 1024);
  transpose_cvt_f32_bf16<<<dim3(32, 32), tb, 0, stream>>>(wv, wvT, 1024);
  transpose_cvt_f32_bf16<<<dim3(32, 32), tb, 0, stream>>>(w1, w1T, 1024);
  transpose_cvt_f32_bf16<<<dim3(32, 32), tb, 0, stream>>>(w2, w2T, 1024);
  embed_kernel<<<dim3(4096), tb, 0, stream>>>(xTok, enc, z);

  for (int l = 0; l < L; ++l) {
    ln_kernel<<<dim3(4096), tb, 0, stream>>>(z, g1, b1, y1);
    run_gemm<1>(y1, wqT, Qb, nullptr, nullptr, Mr, D, D, 0, 0, 0, 1, stream);
    run_gemm<1>(y1, wkT, Kb, nullptr, nullptr, Mr, D, D, 0, 0, 0, 1, stream);
    run_gemm<1>(y1, wvT, Vb, nullptr, nullptr, Mr, D, D, 0, 0, 0, 1, stream);
    run_gemm<0>(Qb, Kb, S, nullptr, nullptr, 1024, 1024, 1024, MM, MM, MM, 4, stream);
    softmax_kernel<<<dim3(4096), tb, 0, stream>>>(S, Pb);
    transpose_bf16_kernel<<<dim3(32, 32, 4), tb, 0, stream>>>(Vb, Vt, 1024);
    run_gemm<0>(Pb, Vt, O, nullptr, nullptr, 1024, 1024, 1024, MM, MM, MM, 4, stream);
    ln_kernel<<<dim3(4096), tb, 0, stream>>>(O, g2, b2, y2);
    run_gemm<2>(y2, w1T, Hb, bb1, nullptr, Mr, D, D, 0, 0, 0, 1, stream);
    run_gemm<3>(Hb, w2T, z, bb2, z, Mr, D, D, 0, 0, 0, 1, stream);
  }

  // Encoder -> bf16 AFTER the loop (encb aliases dead layer buffers, saves 64MB peak ws)
  cvt_f32_bf16<<<dim3(2048), tb, 0, stream>>>(enc, encb, (long long)V * D / 4);
  cvt_f32_bf16<<<dim3(2048), tb, 0, stream>>>(z, zb, (long long)Mr * D / 4);
  run_gemm<0>(zb, encb, logits, nullptr, nullptr, Mr, V, D, 0, 0, 0, 1, stream);
  nll_kernel<<<dim3(4096), tb, 0, stream>>>(logits, yTok, nll);
  mean_kernel<<<dim3(1), tb, 0, stream>>>(nll, lossp);
}

// Round 5
// 1937.359 us; speedup vs baseline: 1.2763x; 1.2763x over previous
//
#include <hip/hip_runtime.h>
#include <hip/hip_bf16.h>
#include <stdint.h>

typedef unsigned short u16;
typedef __attribute__((ext_vector_type(8))) short bf16x8;
typedef __attribute__((ext_vector_type(4))) float f32x4;

#define BK 32

// ---------- helpers ----------
__device__ inline u16 f2bf(float f) {
  __hip_bfloat16 h = __float2bfloat16(f);
  return *reinterpret_cast<u16*>(&h);
}

typedef unsigned int __attribute__((address_space(1)))* gu32p;
typedef unsigned int __attribute__((address_space(3)))* lu32p;

__device__ inline void load_lds16(const void* g, void* l) {
  // async global->LDS, 16B per lane; LDS dest must be wave-uniform base (HW adds lane*16)
  __builtin_amdgcn_global_load_lds((gu32p)(uint64_t)g, (lu32p)(uint32_t)(uint64_t)l, 16, 0, 0);
}

template<int OP>  // 0 = sum, 1 = max
__device__ inline float block_reduce_256(float v, float* sbuf) {
  #pragma unroll
  for (int off = 32; off > 0; off >>= 1) {
    float o = __shfl_down(v, off);
    v = OP ? fmaxf(v, o) : (v + o);
  }
  const int lane = threadIdx.x & 63, w = threadIdx.x >> 6;
  if (lane == 0) sbuf[w] = v;
  __syncthreads();
  float r = OP ? fmaxf(fmaxf(sbuf[0], sbuf[1]), fmaxf(sbuf[2], sbuf[3]))
               : (sbuf[0] + sbuf[1] + sbuf[2] + sbuf[3]);
  __syncthreads();
  return r;
}

// ---------- GEMM: C[M,N] = A[M,K](bf16) * B[N,K](bf16)^T, batched via blockIdx.z ----------
// Tile BM x BN, 4 waves in 2x2, wave tile (BM/2)x(BN/2). Strided A/B/C (lda/ldb/ldc).
// Block raster: XCD-contiguous swizzle (when total%8==0) then GROUP_N=8, pn-fast —
// keeps 8 B-panels (2MB @BN=128) L2-resident per group while A streams once.
// EPI: 0 = f32 out, 1 = bf16 out, 2 = +bias,relu -> bf16, 3 = +bias,+resid -> f32
template<int BM, int BN, int EPI>
__global__ __launch_bounds__(256, 2) void gemm_nt(
    const u16* __restrict__ A, const u16* __restrict__ B, void* Cv,
    const float* __restrict__ bias, const float* resid, int K,
    long long lda, long long ldb, long long ldc,
    long long sA, long long sB, long long sC) {
  constexpr int MR = BM / 32, NR = BN / 32;
  constexpr int AI = BM / 64, BI = BN / 64;  // staging issues (256 lanes x 16B each)
  __shared__ u16 lds[BM * BK + BN * BK];
  u16* As = lds;
  u16* Bs = lds + BM * BK;

  const int tid = threadIdx.x;
  const int lane = tid & 63, wave = tid >> 6;
  const int wr = wave >> 1, wc = wave & 1;
  const int lr = lane & 15, kq = lane >> 4;

  // ---- block raster swizzle ----
  const int npn = gridDim.x, npm = gridDim.y;
  int pid = blockIdx.y * npn + blockIdx.x;
  const int total = npn * npm;
  if ((total & 7) == 0) pid = (pid & 7) * (total >> 3) + (pid >> 3);  // XCD-contiguous
  const int gsize = 8 * npm;
  const int gid = pid / gsize, rem = pid - gid * gsize;
  const int gn0 = gid * 8;
  int gw = npn - gn0; if (gw > 8) gw = 8;
  const int pn = gn0 + rem % gw, pm = rem / gw;
  const int m0 = pm * BM, n0 = pn * BN;

  const int bz = blockIdx.z;
  const u16* Ab = A + (size_t)bz * sA;
  const u16* Bb = B + (size_t)bz * sB;

  f32x4 acc[MR][NR] = {};

  for (int kt = 0; kt < K; kt += BK) {
    #pragma unroll
    for (int i = 0; i < AI; ++i) {
      int t = i * 256 + tid;
      int row = t >> 2;                 // 4 x 16B segments per 64B row (BK=32 bf16)
      int cb = (t & 3) * 16;
      const char* g = (const char*)(Ab + (size_t)(m0 + row) * lda + kt) + cb;
      char* l = (char*)As + (size_t)(i * 256 + wave * 64) * 16;  // wave-uniform
      load_lds16(g, l);
    }
    #pragma unroll
    for (int i = 0; i < BI; ++i) {
      int t = i * 256 + tid;
      int row = t >> 2;
      int cb = (t & 3) * 16;
      const char* g = (const char*)(Bb + (size_t)(n0 + row) * ldb + kt) + cb;
      char* l = (char*)Bs + (size_t)(i * 256 + wave * 64) * 16;
      load_lds16(g, l);
    }
    __syncthreads();

    bf16x8 a[MR], b[NR];
    #pragma unroll
    for (int m = 0; m < MR; ++m)
      a[m] = *(const bf16x8*)(As + (wr * (BM / 2) + m * 16 + lr) * BK + kq * 8);
    #pragma unroll
    for (int n = 0; n < NR; ++n)
      b[n] = *(const bf16x8*)(Bs + (wc * (BN / 2) + n * 16 + lr) * BK + kq * 8);
    #pragma unroll
    for (int m = 0; m < MR; ++m)
      #pragma unroll
      for (int n = 0; n < NR; ++n)
        acc[m][n] = __builtin_amdgcn_mfma_f32_16x16x32_bf16(a[m], b[n], acc[m][n], 0, 0, 0);
    __syncthreads();
  }

  // epilogue: C/D layout col=lane&15, row=(lane>>4)*4+r  [verified m89]
  #pragma unroll
  for (int m = 0; m < MR; ++m) {
    int row = m0 + wr * (BM / 2) + m * 16 + kq * 4;
    #pragma unroll
    for (int n = 0; n < NR; ++n) {
      int col = n0 + wc * (BN / 2) + n * 16 + lr;
      #pragma unroll
      for (int r = 0; r < 4; ++r) {
        float v = acc[m][n][r];
        size_t idx = (size_t)sC * bz + (size_t)(row + r) * ldc + col;
        if (EPI == 0) {
          ((float*)Cv)[idx] = v;
        } else if (EPI == 1) {
          ((u16*)Cv)[idx] = f2bf(v);
        } else if (EPI == 2) {
          v += bias[col];
          ((u16*)Cv)[idx] = f2bf(v > 0.f ? v : 0.f);
        } else {
          ((float*)Cv)[idx] = resid[idx] + v + bias[col];
        }
      }
    }
  }
}

// ---------- LayerNorm (faithful buggy formula): out = (x - mu/sqrt(var)) * g + b, bf16 out ----------
__global__ __launch_bounds__(256) void ln_kernel(const float* __restrict__ x,
                                                 const float* __restrict__ g,
                                                 const float* __restrict__ b,
                                                 u16* __restrict__ out) {
  __shared__ float sbuf[4];
  size_t row = blockIdx.x;
  float4 v = ((const float4*)(x + row * 1024))[threadIdx.x];
  float s = v.x + v.y + v.z + v.w;
  float s2 = v.x * v.x + v.y * v.y + v.z * v.z + v.w * v.w;
  s = block_reduce_256<0>(s, sbuf);
  s2 = block_reduce_256<0>(s2, sbuf);
  float mu = s * (1.f / 1024.f);
  float var = (s2 - 1024.f * mu * mu) * (1.f / 1023.f);  // ddof=1
  float c = mu * rsqrtf(var);
  int col = threadIdx.x * 4;
  ushort4 o;
  o.x = f2bf((v.x - c) * g[col + 0] + b[col + 0]);
  o.y = f2bf((v.y - c) * g[col + 1] + b[col + 1]);
  o.z = f2bf((v.z - c) * g[col + 2] + b[col + 2]);
  o.w = f2bf((v.w - c) * g[col + 3] + b[col + 3]);
  ((ushort4*)(out + row * 1024))[threadIdx.x] = o;
}

// ---------- softmax over rows of S (1024 wide), scale applied pre-softmax, bf16 out ----------
__global__ __launch_bounds__(256) void softmax_kernel(const float* __restrict__ S,
                                                      u16* __restrict__ P) {
  __shared__ float sbuf[4];
  size_t row = blockIdx.x;
  const float scale = 0.03125f;  // 1/sqrt(1024)
  float4 v = ((const float4*)(S + row * 1024))[threadIdx.x];
  v.x *= scale; v.y *= scale; v.z *= scale; v.w *= scale;
  float mx = fmaxf(fmaxf(v.x, v.y), fmaxf(v.z, v.w));
  mx = block_reduce_256<1>(mx, sbuf);
  float e0 = __expf(v.x - mx), e1 = __expf(v.y - mx), e2 = __expf(v.z - mx), e3 = __expf(v.w - mx);
  float sum = block_reduce_256<0>(e0 + e1 + e2 + e3, sbuf);
  float inv = 1.f / sum;
  ushort4 o;
  o.x = f2bf(e0 * inv); o.y = f2bf(e1 * inv); o.z = f2bf(e2 * inv); o.w = f2bf(e3 * inv);
  ((ushort4*)(P + row * 1024))[threadIdx.x] = o;
}

// ---------- transposes ----------
__global__ void transpose_cvt_f32_bf16(const float* __restrict__ in, u16* __restrict__ out, int n) {
  __shared__ float t[32][33];
  int bx = blockIdx.x * 32, by = blockIdx.y * 32;
  int tx = threadIdx.x & 31, ty = threadIdx.x >> 5;
  for (int r = ty; r < 32; r += 8) t[r][tx] = in[(size_t)(by + r) * n + bx + tx];
  __syncthreads();
  for (int r = ty; r < 32; r += 8) out[(size_t)(bx + r) * n + by + tx] = f2bf(t[tx][r]);
}

// out[b][x][y] = in[b*in_batch + y*in_ld + in_col0 + x]  (extracts V^T from fused QKV)
__global__ void transpose_bf16_kernel(const u16* __restrict__ in, u16* __restrict__ out, int n,
                                      long long in_ld, long long in_batch, long long out_batch,
                                      int in_col0) {
  __shared__ u16 t[32][33];
  const u16* ip = in + (size_t)blockIdx.z * in_batch;
  u16* op = out + (size_t)blockIdx.z * out_batch;
  int bx = blockIdx.x * 32, by = blockIdx.y * 32;
  int tx = threadIdx.x & 31, ty = threadIdx.x >> 5;
  for (int r = ty; r < 32; r += 8) t[r][tx] = ip[(size_t)(by + r) * in_ld + in_col0 + bx + tx];
  __syncthreads();
  for (int r = ty; r < 32; r += 8) op[(size_t)(bx + r) * n + by + tx] = t[tx][r];
}

// ---------- misc elementwise ----------
__global__ void cvt_f32_bf16(const float* __restrict__ in, u16* __restrict__ out, long long n4) {
  long long i = (long long)blockIdx.x * 256 + threadIdx.x;
  long long stride = (long long)gridDim.x * 256;
  for (; i < n4; i += stride) {
    float4 v = ((const float4*)in)[i];
    ushort4 o;
    o.x = f2bf(v.x); o.y = f2bf(v.y); o.z = f2bf(v.z); o.w = f2bf(v.w);
    ((ushort4*)out)[i] = o;
  }
}

__global__ void embed_kernel(const int* __restrict__ xTok, const float* __restrict__ enc,
                             float* __restrict__ z) {
  size_t row = blockIdx.x;
  int tok = xTok[row];
  float4 v = ((const float4*)(enc + (size_t)tok * 1024))[threadIdx.x];
  ((float4*)(z + row * 1024))[threadIdx.x] = v;
}

// ---------- loss ----------
__global__ __launch_bounds__(256) void nll_kernel(const float* __restrict__ logits,
                                                  const int* __restrict__ yTok,
                                                  float* __restrict__ nll) {
  __shared__ float sm[4];
  __shared__ float ss[4];
  size_t row = blockIdx.x;
  const float* L = logits + row * 32000;
  float m = -1e30f, s = 0.f;
  for (int i = threadIdx.x; i < 32000; i += 256) {
    float v = L[i];
    if (v > m) { s = s * __expf(m - v) + 1.f; m = v; }
    else       { s += __expf(v - m); }
  }
  #pragma unroll
  for (int off = 32; off > 0; off >>= 1) {
    float mo = __shfl_down(m, off), so = __shfl_down(s, off);
    float mn = fmaxf(m, mo);
    s = s * __expf(m - mn) + so * __expf(mo - mn);
    m = mn;
  }
  int lane = threadIdx.x & 63, w = threadIdx.x >> 6;
  if (lane == 0) { sm[w] = m; ss[w] = s; }
  __syncthreads();
  if (threadIdx.x == 0) {
    float M = fmaxf(fmaxf(sm[0], sm[1]), fmaxf(sm[2], sm[3]));
    float S = ss[0] * __expf(sm[0] - M) + ss[1] * __expf(sm[1] - M) +
              ss[2] * __expf(sm[2] - M) + ss[3] * __expf(sm[3] - M);
    float lse = M + logf(S);
    nll[row] = lse - L[yTok[row]];
  }
}

__global__ __launch_bounds__(256) void mean_kernel(const float* __restrict__ nll,
                                                   float* __restrict__ out) {
  __shared__ float sbuf[4];
  float s = 0.f;
  for (int i = threadIdx.x; i < 4096; i += 256) s += nll[i];
  s = block_reduce_256<0>(s, sbuf);
  if (threadIdx.x == 0) out[0] = s * (1.f / 4096.f);
}

// ---------- launch ----------
template<int BMX, int BNX, int EPI>
static void run_gemm(const void* A, const void* B, void* C, const float* bias, const float* resid,
                     int M, int Ncols, int K,
                     long long lda, long long ldb, long long ldc,
                     long long sA, long long sB, long long sC, int batches, hipStream_t st) {
  dim3 g(Ncols / BNX, M / BMX, batches);
  gemm_nt<BMX, BNX, EPI><<<g, dim3(256), 0, st>>>((const u16*)A, (const u16*)B, C, bias, resid,
                                                  K, lda, ldb, ldc, sA, sB, sC);
}

extern "C" void kernel_launch(void* const* d_in, const int* in_sizes, int n_in,
                              void* d_out, int out_size, void* d_ws, size_t ws_size,
                              hipStream_t stream) {
  const int*   xTok = (const int*)d_in[0];
  const int*   yTok = (const int*)d_in[1];
  const float* enc  = (const float*)d_in[2];
  const float* g1   = (const float*)d_in[3];
  const float* b1   = (const float*)d_in[4];
  const float* wq   = (const float*)d_in[5];
  const float* wk   = (const float*)d_in[6];
  const float* wv   = (const float*)d_in[7];
  const float* g2   = (const float*)d_in[8];
  const float* b2   = (const float*)d_in[9];
  const float* w1   = (const float*)d_in[10];
  const float* bb1  = (const float*)d_in[11];
  const float* w2   = (const float*)d_in[12];
  const float* bb2  = (const float*)d_in[13];

  const int Mr = 4096, D = 1024, V = 32000, L = 6;
  const long long MM = 1024 * 1024;           // 1M elements
  const long long MT = (long long)1024 * 3072;

  size_t off = 0;
  auto alloc = [&](size_t bytes) -> void* {
    void* p = (char*)d_ws + off;
    off += (bytes + 255) & ~(size_t)255;
    return p;
  };
  // Live during the layer loop:
  float* z    = (float*)alloc((size_t)Mr * D * 4);     // 16MB
  float* S    = (float*)alloc((size_t)Mr * 1024 * 4);  // 16MB
  float* O    = (float*)alloc((size_t)Mr * D * 4);     // 16MB
  u16*   y1   = (u16*)alloc((size_t)Mr * D * 2);       //  8MB
  u16*   y2   = (u16*)alloc((size_t)Mr * D * 2);       //  8MB
  u16*   QKVb = (u16*)alloc((size_t)Mr * 3 * D * 2);   // 24MB
  u16*   Vt   = (u16*)alloc((size_t)Mr * D * 2);       //  8MB
  u16*   Pb   = (u16*)alloc((size_t)Mr * D * 2);       //  8MB
  u16*   wqkvT= (u16*)alloc((size_t)3 * D * D * 2);    //  6MB
  u16*   w1T  = (u16*)alloc((size_t)D * D * 2);
  u16*   w2T  = (u16*)alloc((size_t)D * D * 2);
  float* nll  = (float*)alloc(4096 * 4);
  u16*   Hb = QKVb;        // reuse (QKV dead after PV)
  // Post-loop aliases (dead once the last FF2 wrote z):
  u16*   encb = (u16*)S;   // 72MB span = S(16)+O(16)+y1(8)+y2(8)+QKVb(24) >= 64MB
  u16*   zb   = Vt;        // 8MB

  float* logits = (float*)d_out;
  float* lossp  = logits + (size_t)Mr * V;

  dim3 tb(256);
  transpose_cvt_f32_bf16<<<dim3(32, 32), tb, 0, stream>>>(wq, wqkvT, 1024);
  transpose_cvt_f32_bf16<<<dim3(32, 32), tb, 0, stream>>>(wk, wqkvT + (size_t)D * D, 1024);
  transpose_cvt_f32_bf16<<<dim3(32, 32), tb, 0, stream>>>(wv, wqkvT + (size_t)2 * D * D, 1024);
  transpose_cvt_f32_bf16<<<dim3(32, 32), tb, 0, stream>>>(w1, w1T, 1024);
  transpose_cvt_f32_bf16<<<dim3(32, 32), tb, 0, stream>>>(w2, w2T, 1024);
  embed_kernel<<<dim3(4096), tb, 0, stream>>>(xTok, enc, z);

  for (int l = 0; l < L; ++l) {
    ln_kernel<<<dim3(4096), tb, 0, stream>>>(z, g1, b1, y1);
    // fused QKV: [4096,1024] x [3072,1024]^T -> [4096,3072] bf16
    run_gemm<128, 128, 1>(y1, wqkvT, QKVb, nullptr, nullptr, Mr, 3 * D, D,
                          D, D, 3 * D, 0, 0, 0, 1, stream);
    // QK^T per batch: Q rows (lda=3072), K rows (ldb=3072) -> S f32
    run_gemm<64, 64, 0>(QKVb, QKVb + D, S, nullptr, nullptr, 1024, 1024, D,
                        3 * D, 3 * D, 1024, MT, MT, MM, 4, stream);
    softmax_kernel<<<dim3(4096), tb, 0, stream>>>(S, Pb);
    // V^T per batch from fused buffer
    transpose_bf16_kernel<<<dim3(32, 32, 4), tb, 0, stream>>>(QKVb, Vt, 1024, 3 * D, MT, MM, 2 * D);
    // P x V^T -> O f32
    run_gemm<64, 64, 0>(Pb, Vt, O, nullptr, nullptr, 1024, 1024, D,
                        1024, 1024, 1024, MM, MM, MM, 4, stream);
    ln_kernel<<<dim3(4096), tb, 0, stream>>>(O, g2, b2, y2);
    run_gemm<64, 64, 2>(y2, w1T, Hb, bb1, nullptr, Mr, D, D,
                        D, D, D, 0, 0, 0, 1, stream);
    run_gemm<64, 64, 3>(Hb, w2T, z, bb2, z, Mr, D, D,
                        D, D, D, 0, 0, 0, 1, stream);
  }

  // Encoder -> bf16 AFTER the loop (encb aliases dead layer buffers)
  cvt_f32_bf16<<<dim3(2048), tb, 0, stream>>>(enc, encb, (long long)V * D / 4);
  cvt_f32_bf16<<<dim3(2048), tb, 0, stream>>>(z, zb, (long long)Mr * D / 4);
  run_gemm<128, 128, 0>(zb, encb, logits, nullptr, nullptr, Mr, V, D,
                        D, D, V, 0, 0, 0, 1, stream);
  nll_kernel<<<dim3(4096), tb, 0, stream>>>(logits, yTok, nll);
  mean_kernel<<<dim3(1), tb, 0, stream>>>(nll, lossp);
}